// Round 7
// baseline (279.842 us; speedup 1.0000x reference)
//
#include <hip/hip_runtime.h>
#include <cstdint>
#include <cstddef>

#define B_ 4
#define TQ_ 1024
#define TKV_ 1024
#define D_ 1024
#define H_ 16
#define HD_ 64

typedef __bf16 bf16_t;
typedef bf16_t bf16x4 __attribute__((ext_vector_type(4)));
typedef bf16_t bf16x8 __attribute__((ext_vector_type(8)));
typedef float f32x4 __attribute__((ext_vector_type(4)));

#if __has_builtin(__builtin_amdgcn_exp2f)
#define EXP2F __builtin_amdgcn_exp2f
#else
#define EXP2F exp2f
#endif

__device__ __forceinline__ bf16_t to_bf16(float f) {
  uint32_t u = __builtin_bit_cast(uint32_t, f);
  u += 0x7fffu + ((u >> 16) & 1u);
  uint16_t h = (uint16_t)(u >> 16);
  return __builtin_bit_cast(bf16_t, h);
}
__device__ __forceinline__ float bf2f(bf16_t b) {
  uint32_t u = ((uint32_t)__builtin_bit_cast(uint16_t, b)) << 16;
  return __builtin_bit_cast(float, u);
}
// pack two fp32 -> two bf16 (truncation) in ONE v_perm_b32
__device__ __forceinline__ uint32_t pack_bf16_trunc(float lo, float hi) {
  return __builtin_amdgcn_perm(__builtin_bit_cast(uint32_t, hi),
                               __builtin_bit_cast(uint32_t, lo), 0x07060302u);
}
__device__ __forceinline__ void gload_lds16(const void* g, void* l) {
  __builtin_amdgcn_global_load_lds((const __attribute__((address_space(1))) void*)g,
                                   (__attribute__((address_space(3))) void*)l, 16, 0, 0);
}

// ---------------- prep: f2b of activations + weight transpose + zero(part) ----------------
__global__ __launch_bounds__(256) void k_prep(const float* __restrict__ xq,
                                              const float* __restrict__ xkv,
                                              const float* __restrict__ Wq,
                                              const float* __restrict__ Wkv,
                                              const float* __restrict__ Wc,
                                              bf16_t* __restrict__ oq,
                                              bf16_t* __restrict__ okv,
                                              bf16_t* __restrict__ Wqt,
                                              bf16_t* __restrict__ Wkvt,
                                              bf16_t* __restrict__ Wct,
                                              float* __restrict__ part) {
  int blk = blockIdx.x;
  if (blk == 0 && threadIdx.x < 128) part[threadIdx.x] = 0.f;
  if (blk < 8192) {
    const float* in = (blk < 4096) ? xq : xkv;
    bf16_t* out = (blk < 4096) ? oq : okv;
    int i = (blk & 4095) * 256 + threadIdx.x;
    float4 v = ((const float4*)in)[i];
    bf16x4 o = {to_bf16(v.x), to_bf16(v.y), to_bf16(v.z), to_bf16(v.w)};
    *(bf16x4*)(out + (size_t)i * 4) = o;
  } else {
    __shared__ float tile[32][33];
    int t = blk - 8192;             // 0..6143
    int x = t % 192, yb = t / 192;  // yb 0..31
    const float* in;
    bf16_t* out;
    int C, c0;
    if (x < 64) { in = Wq; out = Wqt; C = 2048; c0 = x * 32; }
    else if (x < 160) { in = Wkv; out = Wkvt; C = 3072; c0 = (x - 64) * 32; }
    else { in = Wc; out = Wct; C = 1024; c0 = (x - 160) * 32; }
    int r0 = yb * 32;
    int tx = threadIdx.x & 31, ty = threadIdx.x >> 5;
#pragma unroll
    for (int i = 0; i < 4; i++)
      tile[ty + i * 8][tx] = in[(size_t)(r0 + ty + i * 8) * C + c0 + tx];
    __syncthreads();
#pragma unroll
    for (int i = 0; i < 4; i++) {
      int rr = ty + i * 8;
      out[(size_t)(c0 + rr) * 1024 + r0 + tx] = to_bf16(tile[tx][rr]);
    }
  }
}

// ---------------- merged Q+KV projection GEMM, XCD-supertiled, BK=64, XOR-swizzled LDS ----
// LDS layout: granule g (8 bf16) of row r stored at position g^(r&7) -> b128 frag
// reads are 2-way conflict-free. BK=64 halves the barrier-drain count.
__global__ __launch_bounds__(256, 2) void k_gemm_qkv(const bf16_t* __restrict__ xq,
                                                     const bf16_t* __restrict__ xkv,
                                                     const bf16_t* __restrict__ Wqt,
                                                     const bf16_t* __restrict__ Wkvt,
                                                     const float* __restrict__ kn1,
                                                     const float* __restrict__ kn2,
                                                     bf16_t* __restrict__ q12,
                                                     bf16_t* __restrict__ k1h,
                                                     bf16_t* __restrict__ k2h,
                                                     bf16_t* __restrict__ vt) {
  __shared__ bf16_t As[128 * 64];
  __shared__ bf16_t Bs[128 * 64];
  const int tid = threadIdx.x;
  const int wave = tid >> 6, lane = tid & 63;
  const int ln = lane & 15, lq = lane >> 4;
  const int swz = ln & 7;

  const int fid = blockIdx.x;
  const int xcd = fid & 7, l = fid >> 3;  // l in [0,160)
  bool isq;
  int xb, yb;
  if (l < 64) {
    isq = true;
    xb = (xcd & 3) * 4 + (l & 3);
    yb = (xcd >> 2) * 16 + (l >> 2);
  } else {
    isq = false;
    int l2 = l - 64;
    xb = (xcd & 3) * 6 + l2 % 6;
    yb = (xcd >> 2) * 16 + l2 / 6;
  }
  const bf16_t* A = isq ? xq : xkv;
  const bf16_t* Bt = isq ? Wqt : Wkvt;
  const int n0 = xb * 128, m0 = yb * 128;
  const int wm = (wave >> 1) * 64, wn = (wave & 1) * 64;
  f32x4 acc[4][4];
#pragma unroll
  for (int i = 0; i < 4; i++)
#pragma unroll
    for (int j = 0; j < 4; j++) acc[i][j] = (f32x4){0.f, 0.f, 0.f, 0.f};

  for (int k0 = 0; k0 < 1024; k0 += 64) {
#pragma unroll
    for (int r = 0; r < 8; r++) {
      int g = (r & 3) * 256 + tid;  // region-local granule 0..1023
      int row = g >> 3;
      int dg = (g & 7) ^ (row & 7);
      const bf16_t* src = (r < 4) ? (A + (size_t)(m0 + row) * 1024 + k0 + dg * 8)
                                  : (Bt + (size_t)(n0 + row) * 1024 + k0 + dg * 8);
      char* dst = ((r < 4) ? (char*)As : (char*)Bs) + ((r & 3) * 256 + wave * 64) * 16;
      gload_lds16(src, dst);
    }
    asm volatile("s_waitcnt vmcnt(0)" ::: "memory");
    __syncthreads();
#pragma unroll
    for (int ks = 0; ks < 2; ks++) {
      bf16x8 af[4], bfr[4];
#pragma unroll
      for (int i = 0; i < 4; i++) {
        af[i] = *(const bf16x8*)(As + ((wm + i * 16 + ln) * 8 + ((ks * 4 + lq) ^ swz)) * 8);
        bfr[i] = *(const bf16x8*)(Bs + ((wn + i * 16 + ln) * 8 + ((ks * 4 + lq) ^ swz)) * 8);
      }
#pragma unroll
      for (int i = 0; i < 4; i++)
#pragma unroll
        for (int j = 0; j < 4; j++)
          acc[i][j] = __builtin_amdgcn_mfma_f32_16x16x32_bf16(af[i], bfr[j], acc[i][j], 0, 0, 0);
    }
    __syncthreads();
  }

  if (isq) {
#pragma unroll
    for (int i = 0; i < 4; i++)
#pragma unroll
      for (int j = 0; j < 4; j++)
#pragma unroll
        for (int r = 0; r < 4; r++) {
          int row = m0 + wm + i * 16 + lq * 4 + r;
          int col = n0 + wn + j * 16 + ln;
          q12[(size_t)row * 2048 + col] = to_bf16(acc[i][j][r]);
        }
  } else {
    const int col0 = n0 + wn;
    const int part3 = col0 >> 10;  // 0:k1, 1:k2, 2:v
    const int h = (col0 >> 6) & 15;
    const int b = m0 >> 10;
    const int bh = b * 16 + h;
    if (part3 < 2) {
      const float* kn = part3 ? kn2 : kn1;
      bf16_t* dst = part3 ? k2h : k1h;
      float kw[4];
#pragma unroll
      for (int j = 0; j < 4; j++) kw[j] = kn[j * 16 + ln];
#pragma unroll
      for (int i = 0; i < 4; i++)
#pragma unroll
        for (int r = 0; r < 4; r++) {
          float ss = 0.f;
#pragma unroll
          for (int j = 0; j < 4; j++) ss += acc[i][j][r] * acc[i][j][r];
          ss += __shfl_xor(ss, 1, 64);
          ss += __shfl_xor(ss, 2, 64);
          ss += __shfl_xor(ss, 4, 64);
          ss += __shfl_xor(ss, 8, 64);
          float rstd = rsqrtf(ss * (1.f / 64.f) + 1e-5f);
          int m = m0 + wm + i * 16 + lq * 4 + r;
          int t = m & 1023;
          size_t base = ((size_t)bh * 1024 + t) * 64;
#pragma unroll
          for (int j = 0; j < 4; j++)
            dst[base + j * 16 + ln] = to_bf16(acc[i][j][r] * rstd * kw[j]);
        }
    } else {
      // V: vt'[bh][d][t'], t' permuted within each 32-block:
      // kv = h16*16 + lqw*4 + r  ->  t' = lqw*8 + h16*4 + r
      bf16_t* obase = vt + (size_t)bh * 65536;
#pragma unroll
      for (int i = 0; i < 4; i++) {
        int t0 = (m0 & 1023) + wm + i * 16 + lq * 4;
        int tp = (t0 & ~31) | (((t0 >> 2) & 3) << 3) | (((t0 >> 4) & 1) << 2);
#pragma unroll
        for (int j = 0; j < 4; j++) {
          bf16x4 pv;
#pragma unroll
          for (int r = 0; r < 4; r++) pv[r] = to_bf16(acc[i][j][r]);
          *(bf16x4*)(obase + (size_t)(j * 16 + ln) * 1024 + tp) = pv;
        }
      }
    }
  }
}

// ---------------- bf16 GEMM 128x64 tile (fp32 out), XCD-supertiled, BK=64, swizzled ----------------
__global__ __launch_bounds__(256, 2) void k_gemm64(const bf16_t* __restrict__ A,
                                                   const bf16_t* __restrict__ Bt,
                                                   float* __restrict__ C, int N, int K) {
  __shared__ bf16_t As[128 * 64];
  __shared__ bf16_t Bs[64 * 64];
  const int tid = threadIdx.x;
  const int wave = tid >> 6, lane = tid & 63;
  const int ln = lane & 15, lq = lane >> 4;
  const int swz = ln & 7;
  const int fid = blockIdx.x;             // flat 512
  const int xcd = fid & 7, l = fid >> 3;  // 0..63
  const int lx = l & 1, ly = (l >> 1) & 15, yh = l >> 5;
  const int n0 = (xcd * 2 + lx) * 64;
  const int m0 = (yh * 16 + ly) * 128;
  const int wm = wave * 32;
  f32x4 acc[2][4];
#pragma unroll
  for (int i = 0; i < 2; i++)
#pragma unroll
    for (int j = 0; j < 4; j++) acc[i][j] = (f32x4){0.f, 0.f, 0.f, 0.f};

  for (int k0 = 0; k0 < K; k0 += 64) {
#pragma unroll
    for (int r = 0; r < 6; r++) {
      int g = ((r < 4) ? (r & 3) : (r - 4)) * 256 + tid;
      int row = g >> 3;
      int dg = (g & 7) ^ (row & 7);
      const bf16_t* src = (r < 4) ? (A + (size_t)(m0 + row) * K + k0 + dg * 8)
                                  : (Bt + (size_t)(n0 + row) * K + k0 + dg * 8);
      char* dst = ((r < 4) ? (char*)As + (r & 3) * 4096 : (char*)Bs + (r - 4) * 4096) +
                  (wave * 64) * 16;
      gload_lds16(src, dst);
    }
    asm volatile("s_waitcnt vmcnt(0)" ::: "memory");
    __syncthreads();
#pragma unroll
    for (int ks = 0; ks < 2; ks++) {
      bf16x8 af[2], bfr[4];
#pragma unroll
      for (int i = 0; i < 2; i++)
        af[i] = *(const bf16x8*)(As + ((wm + i * 16 + ln) * 8 + ((ks * 4 + lq) ^ swz)) * 8);
#pragma unroll
      for (int j = 0; j < 4; j++)
        bfr[j] = *(const bf16x8*)(Bs + ((j * 16 + ln) * 8 + ((ks * 4 + lq) ^ swz)) * 8);
#pragma unroll
      for (int i = 0; i < 2; i++)
#pragma unroll
        for (int j = 0; j < 4; j++)
          acc[i][j] = __builtin_amdgcn_mfma_f32_16x16x32_bf16(af[i], bfr[j], acc[i][j], 0, 0, 0);
    }
    __syncthreads();
  }
#pragma unroll
  for (int i = 0; i < 2; i++)
#pragma unroll
    for (int j = 0; j < 4; j++)
#pragma unroll
      for (int r = 0; r < 4; r++) {
        int row = m0 + wm + i * 16 + lq * 4 + r;
        int col = n0 + j * 16 + ln;
        C[(size_t)row * N + col] = acc[i][j][r];
      }
}

// ---------------- fused dual-stream flash attention + GN partial stats ----------------
// grid (64=bh, 8=qblock); block 256 = 4 waves x 32 q-rows.
// 128 KV staged per barrier (48 KB), processed as two 64-KV halves -> half the drains.
__global__ __launch_bounds__(256, 2) void k_attn2(const bf16_t* __restrict__ q12,
                                                  const bf16_t* __restrict__ k1h,
                                                  const bf16_t* __restrict__ k2h,
                                                  const bf16_t* __restrict__ vt,
                                                  const float* __restrict__ qn1,
                                                  const float* __restrict__ qn2,
                                                  const float* __restrict__ lmb,
                                                  bf16_t* __restrict__ y,
                                                  float* __restrict__ part) {
  __shared__ bf16_t Ks[2][8192];  // [kv 0..127][d] XOR-swizzled 16B granules
  __shared__ bf16_t Vs[8192];     // [d][t' 0..127] XOR-swizzled 16B granules
  __shared__ float red[8];
  const int tid = threadIdx.x;
  const int wave = tid >> 6, lane = tid & 63;
  const int ln = lane & 15, lq = lane >> 4;
  const int swz = ln & 7;
  const int bh = blockIdx.x;
  const int b = bh >> 4, h = bh & 15;
  const int q0 = blockIdx.y * 128 + wave * 32;
  const bf16_t* kb[2] = {k1h + (size_t)bh * 65536, k2h + (size_t)bh * 65536};
  const bf16_t* vb = vt + (size_t)bh * 65536;

  // ---- Q load (2 streams x 2 m-tiles) + fused RMSNorm * qn * (0.125*log2e) ----
  bf16x8 qf[2][2][2];  // [stream][mt][ks]
#pragma unroll
  for (int st = 0; st < 2; st++)
#pragma unroll
    for (int mt = 0; mt < 2; mt++)
#pragma unroll
      for (int ks = 0; ks < 2; ks++)
        qf[st][mt][ks] = *(const bf16x8*)(q12 + (size_t)(b * 1024 + q0 + mt * 16 + ln) * 2048 +
                                          st * 1024 + h * 64 + ks * 32 + lq * 8);
#pragma unroll
  for (int st = 0; st < 2; st++)
#pragma unroll
    for (int mt = 0; mt < 2; mt++) {
      const float* qn = st ? qn2 : qn1;
      float ssq = 0.f;
#pragma unroll
      for (int ks = 0; ks < 2; ks++)
#pragma unroll
        for (int j = 0; j < 8; j++) {
          float v = bf2f(qf[st][mt][ks][j]);
          ssq += v * v;
        }
      ssq += __shfl_xor(ssq, 16, 64);
      ssq += __shfl_xor(ssq, 32, 64);
      float rr = rsqrtf(ssq * (1.f / 64.f) + 1e-5f) * (0.125f * 1.44269504f);
#pragma unroll
      for (int ks = 0; ks < 2; ks++)
#pragma unroll
        for (int j = 0; j < 8; j++)
          qf[st][mt][ks][j] = to_bf16(bf2f(qf[st][mt][ks][j]) * rr * qn[ks * 32 + lq * 8 + j]);
    }

  f32x4 O[2][2][4];  // [stream][mt][nt]
  float lp[2][2] = {{0.f, 0.f}, {0.f, 0.f}};
#pragma unroll
  for (int st = 0; st < 2; st++)
#pragma unroll
    for (int mt = 0; mt < 2; mt++)
#pragma unroll
      for (int nt = 0; nt < 4; nt++) O[st][mt][nt] = (f32x4){0.f, 0.f, 0.f, 0.f};

  for (int kv0 = 0; kv0 < TKV_; kv0 += 128) {
    __syncthreads();
#pragma unroll
    for (int r = 0; r < 12; r++) {
      int reg = r >> 2;               // 0:K1, 1:K2, 2:V
      int g = (r & 3) * 256 + tid;    // region-local granule 0..1023
      const bf16_t* src;
      if (reg < 2) {
        int row = g >> 3;
        int dg = (g & 7) ^ (row & 7);
        src = kb[reg] + (size_t)(kv0 + row) * 64 + dg * 8;
      } else {
        int row = g >> 4;
        int p = g & 15;
        int dg = (p & 8) | ((p & 7) ^ (row & 7));
        src = vb + (size_t)row * 1024 + kv0 + dg * 8;
      }
      char* dst = ((reg < 2) ? (char*)Ks[reg] : (char*)Vs) + ((r & 3) * 256 + wave * 64) * 16;
      gload_lds16(src, dst);
    }
    asm volatile("s_waitcnt vmcnt(0)" ::: "memory");
    __syncthreads();

#pragma unroll
    for (int cc = 0; cc < 2; cc++) {
      // V B-frags: ONE b128 per (u,nt), shared by both streams and both m-tiles
      bf16x8 vf[2][4];
#pragma unroll
      for (int u = 0; u < 2; u++)
#pragma unroll
        for (int nt = 0; nt < 4; nt++)
          vf[u][nt] =
              *(const bf16x8*)(Vs + ((nt * 16 + ln) * 16 + cc * 8 + ((u * 4 + lq) ^ swz)) * 8);

#pragma unroll
      for (int st = 0; st < 2; st++) {
        bf16x8 kf[2][4];
#pragma unroll
        for (int ks = 0; ks < 2; ks++)
#pragma unroll
          for (int t = 0; t < 4; t++)
            kf[ks][t] = *(const bf16x8*)(&Ks[st][((cc * 64 + t * 16 + ln) * 8 +
                                                  ((ks * 4 + lq) ^ swz)) * 8]);
#pragma unroll
        for (int mt = 0; mt < 2; mt++) {
          f32x4 s[4];
#pragma unroll
          for (int t = 0; t < 4; t++) s[t] = (f32x4){0.f, 0.f, 0.f, 0.f};
#pragma unroll
          for (int ks = 0; ks < 2; ks++)
#pragma unroll
            for (int t = 0; t < 4; t++)
              s[t] =
                  __builtin_amdgcn_mfma_f32_16x16x32_bf16(kf[ks][t], qf[st][mt][ks], s[t], 0, 0, 0);
          uint32_t pfu[2][4];
          float l = 0.f;
#pragma unroll
          for (int t = 0; t < 4; t++) {
            float e0 = EXP2F(s[t][0]), e1 = EXP2F(s[t][1]);
            float e2 = EXP2F(s[t][2]), e3 = EXP2F(s[t][3]);
            l += (e0 + e1) + (e2 + e3);
            pfu[t >> 1][(t & 1) * 2] = pack_bf16_trunc(e0, e1);
            pfu[t >> 1][(t & 1) * 2 + 1] = pack_bf16_trunc(e2, e3);
          }
          lp[st][mt] += l;
#pragma unroll
          for (int u = 0; u < 2; u++) {
            bf16x8 pf = __builtin_bit_cast(bf16x8, *(uint4*)pfu[u]);
#pragma unroll
            for (int nt = 0; nt < 4; nt++)
              O[st][mt][nt] =
                  __builtin_amdgcn_mfma_f32_16x16x32_bf16(pf, vf[u][nt], O[st][mt][nt], 0, 0, 0);
          }
        }
      }
    }
  }

  float c = log1pf(__expf(lmb[h]));
  float s_acc = 0.f, ss_acc = 0.f;
#pragma unroll
  for (int mt = 0; mt < 2; mt++) {
    float linv[2][4];
#pragma unroll
    for (int st = 0; st < 2; st++) {
      float l = lp[st][mt];
      l += __shfl_xor(l, 16, 64);
      l += __shfl_xor(l, 32, 64);
#pragma unroll
      for (int r = 0; r < 4; r++) linv[st][r] = 1.f / __shfl(l, lq * 4 + r, 64);
    }
#pragma unroll
    for (int nt = 0; nt < 4; nt++)
#pragma unroll
      for (int r = 0; r < 4; r++) {
        size_t a = ((size_t)bh * TQ_ + q0 + mt * 16 + lq * 4 + r) * 64 + nt * 16 + ln;
        float val = O[0][mt][nt][r] * linv[0][r] - c * O[1][mt][nt][r] * linv[1][r];
        s_acc += val;
        ss_acc += val * val;
        y[a] = to_bf16(val);
      }
  }
  // GN partial stats: wave-reduce -> LDS -> one atomic pair per block
#pragma unroll
  for (int m = 1; m < 64; m <<= 1) {
    s_acc += __shfl_xor(s_acc, m, 64);
    ss_acc += __shfl_xor(ss_acc, m, 64);
  }
  if (lane == 0) {
    red[wave] = s_acc;
    red[4 + wave] = ss_acc;
  }
  __syncthreads();
  if (tid == 0) {
    atomicAdd(&part[bh * 2], red[0] + red[1] + red[2] + red[3]);
    atomicAdd(&part[bh * 2 + 1], red[4] + red[5] + red[6] + red[7]);
  }
}

// ---------------- GroupNorm apply (stats from part) + layout to (B,TQ,D) bf16 ----------------
__global__ __launch_bounds__(256) void k_gn_apply(const bf16_t* __restrict__ y,
                                                  const float* __restrict__ part,
                                                  const float* __restrict__ gw,
                                                  const float* __restrict__ gb,
                                                  bf16_t* __restrict__ yn) {
  int idx = blockIdx.x * 256 + threadIdx.x;
  int i = idx * 8;
  int bh = i >> 16;
  int h = bh & 15, b = bh >> 4;
  float S = part[bh * 2], SS = part[bh * 2 + 1];
  float mean = S * (1.f / 65536.f);
  float var = SS * (1.f / 65536.f) - mean * mean;
  float rstd = rsqrtf(var + 1e-5f);
  bf16x8 a = *(const bf16x8*)(y + i);
  int rem = i & 65535;
  int t = rem >> 6, d = rem & 63;
  bf16x8 o;
#pragma unroll
  for (int j = 0; j < 8; j++) {
    float f = (bf2f(a[j]) - mean) * rstd * gw[h * 64 + d + j] + gb[h * 64 + d + j];
    o[j] = to_bf16(f);
  }
  *(bf16x8*)(yn + ((size_t)(b * 1024 + t)) * 1024 + h * 64 + d) = o;
}

extern "C" void kernel_launch(void* const* d_in, const int* in_sizes, int n_in,
                              void* d_out, int out_size, void* d_ws, size_t ws_size,
                              hipStream_t stream) {
  const float* x_q = (const float*)d_in[0];
  const float* x_kv = (const float*)d_in[1];
  const float* Wq = (const float*)d_in[2];
  const float* Wkv = (const float*)d_in[3];
  const float* Wc = (const float*)d_in[4];
  const float* qn1 = (const float*)d_in[5];
  const float* kn1 = (const float*)d_in[6];
  const float* qn2 = (const float*)d_in[7];
  const float* kn2 = (const float*)d_in[8];
  const float* gn_w = (const float*)d_in[9];
  const float* gn_b = (const float*)d_in[10];
  const float* lmb = (const float*)d_in[11];

  const size_t MB = (size_t)1 << 20;
  char* ws = (char*)d_ws;
  bf16_t* xq_bf = (bf16_t*)(ws + 0 * MB);
  bf16_t* xkv_bf = (bf16_t*)(ws + 8 * MB);
  bf16_t* Wqt = (bf16_t*)(ws + 16 * MB);
  bf16_t* Wkvt = (bf16_t*)(ws + 20 * MB);
  bf16_t* Wct = (bf16_t*)(ws + 26 * MB);
  bf16_t* q12 = (bf16_t*)(ws + 28 * MB);
  bf16_t* k1h = (bf16_t*)(ws + 44 * MB);
  bf16_t* k2h = (bf16_t*)(ws + 52 * MB);
  bf16_t* vt = (bf16_t*)(ws + 60 * MB);
  bf16_t* y = (bf16_t*)(ws + 68 * MB);
  bf16_t* yn = (bf16_t*)(ws + 76 * MB);
  float* part = (float*)(ws + 84 * MB);  // 128 floats

  k_prep<<<14336, 256, 0, stream>>>(x_q, x_kv, Wq, Wkv, Wc, xq_bf, xkv_bf, Wqt, Wkvt, Wct,
                                    part);
  k_gemm_qkv<<<1280, 256, 0, stream>>>(xq_bf, xkv_bf, Wqt, Wkvt, kn1, kn2, q12, k1h, k2h,
                                       vt);
  k_attn2<<<dim3(64, 8), 256, 0, stream>>>(q12, k1h, k2h, vt, qn1, qn2, lmb, y, part);
  k_gn_apply<<<2048, 256, 0, stream>>>(y, part, gn_w, gn_b, yn);
  k_gemm64<<<512, 256, 0, stream>>>(yn, Wct, (float*)d_out, 1024, 1024);
}

// Round 8
// 223.745 us; speedup vs baseline: 1.2507x; 1.2507x over previous
//
#include <hip/hip_runtime.h>
#include <cstdint>
#include <cstddef>

#define B_ 4
#define TQ_ 1024
#define TKV_ 1024
#define D_ 1024
#define H_ 16
#define HD_ 64

typedef __bf16 bf16_t;
typedef bf16_t bf16x4 __attribute__((ext_vector_type(4)));
typedef bf16_t bf16x8 __attribute__((ext_vector_type(8)));
typedef float f32x4 __attribute__((ext_vector_type(4)));

#if __has_builtin(__builtin_amdgcn_exp2f)
#define EXP2F __builtin_amdgcn_exp2f
#else
#define EXP2F exp2f
#endif

__device__ __forceinline__ bf16_t to_bf16(float f) {
  uint32_t u = __builtin_bit_cast(uint32_t, f);
  u += 0x7fffu + ((u >> 16) & 1u);
  uint16_t h = (uint16_t)(u >> 16);
  return __builtin_bit_cast(bf16_t, h);
}
__device__ __forceinline__ float bf2f(bf16_t b) {
  uint32_t u = ((uint32_t)__builtin_bit_cast(uint16_t, b)) << 16;
  return __builtin_bit_cast(float, u);
}
// pack two fp32 -> two bf16 (truncation) in ONE v_perm_b32
__device__ __forceinline__ uint32_t pack_bf16_trunc(float lo, float hi) {
  return __builtin_amdgcn_perm(__builtin_bit_cast(uint32_t, hi),
                               __builtin_bit_cast(uint32_t, lo), 0x07060302u);
}
__device__ __forceinline__ void gload_lds16(const void* g, void* l) {
  __builtin_amdgcn_global_load_lds((const __attribute__((address_space(1))) void*)g,
                                   (__attribute__((address_space(3))) void*)l, 16, 0, 0);
}

// ---------------- prep: f2b of activations + weight transpose + zero(part) ----------------
__global__ __launch_bounds__(256) void k_prep(const float* __restrict__ xq,
                                              const float* __restrict__ xkv,
                                              const float* __restrict__ Wq,
                                              const float* __restrict__ Wkv,
                                              const float* __restrict__ Wc,
                                              bf16_t* __restrict__ oq,
                                              bf16_t* __restrict__ okv,
                                              bf16_t* __restrict__ Wqt,
                                              bf16_t* __restrict__ Wkvt,
                                              bf16_t* __restrict__ Wct,
                                              float* __restrict__ part) {
  int blk = blockIdx.x;
  if (blk == 0 && threadIdx.x < 128) part[threadIdx.x] = 0.f;
  if (blk < 8192) {
    const float* in = (blk < 4096) ? xq : xkv;
    bf16_t* out = (blk < 4096) ? oq : okv;
    int i = (blk & 4095) * 256 + threadIdx.x;
    float4 v = ((const float4*)in)[i];
    bf16x4 o = {to_bf16(v.x), to_bf16(v.y), to_bf16(v.z), to_bf16(v.w)};
    *(bf16x4*)(out + (size_t)i * 4) = o;
  } else {
    __shared__ float tile[32][33];
    int t = blk - 8192;             // 0..6143
    int x = t % 192, yb = t / 192;  // yb 0..31
    const float* in;
    bf16_t* out;
    int C, c0;
    if (x < 64) { in = Wq; out = Wqt; C = 2048; c0 = x * 32; }
    else if (x < 160) { in = Wkv; out = Wkvt; C = 3072; c0 = (x - 64) * 32; }
    else { in = Wc; out = Wct; C = 1024; c0 = (x - 160) * 32; }
    int r0 = yb * 32;
    int tx = threadIdx.x & 31, ty = threadIdx.x >> 5;
#pragma unroll
    for (int i = 0; i < 4; i++)
      tile[ty + i * 8][tx] = in[(size_t)(r0 + ty + i * 8) * C + c0 + tx];
    __syncthreads();
#pragma unroll
    for (int i = 0; i < 4; i++) {
      int rr = ty + i * 8;
      out[(size_t)(c0 + rr) * 1024 + r0 + tx] = to_bf16(tile[tx][rr]);
    }
  }
}

// ---------------- merged Q+KV projection GEMM, XCD-supertiled, BK=64, XOR-swizzled LDS ----
__global__ __launch_bounds__(256, 2) void k_gemm_qkv(const bf16_t* __restrict__ xq,
                                                     const bf16_t* __restrict__ xkv,
                                                     const bf16_t* __restrict__ Wqt,
                                                     const bf16_t* __restrict__ Wkvt,
                                                     const float* __restrict__ kn1,
                                                     const float* __restrict__ kn2,
                                                     bf16_t* __restrict__ q12,
                                                     bf16_t* __restrict__ k1h,
                                                     bf16_t* __restrict__ k2h,
                                                     bf16_t* __restrict__ vt) {
  __shared__ bf16_t As[128 * 64];
  __shared__ bf16_t Bs[128 * 64];
  const int tid = threadIdx.x;
  const int wave = tid >> 6, lane = tid & 63;
  const int ln = lane & 15, lq = lane >> 4;
  const int swz = ln & 7;

  const int fid = blockIdx.x;
  const int xcd = fid & 7, l = fid >> 3;  // l in [0,160)
  bool isq;
  int xb, yb;
  if (l < 64) {
    isq = true;
    xb = (xcd & 3) * 4 + (l & 3);
    yb = (xcd >> 2) * 16 + (l >> 2);
  } else {
    isq = false;
    int l2 = l - 64;
    xb = (xcd & 3) * 6 + l2 % 6;
    yb = (xcd >> 2) * 16 + l2 / 6;
  }
  const bf16_t* A = isq ? xq : xkv;
  const bf16_t* Bt = isq ? Wqt : Wkvt;
  const int n0 = xb * 128, m0 = yb * 128;
  const int wm = (wave >> 1) * 64, wn = (wave & 1) * 64;
  f32x4 acc[4][4];
#pragma unroll
  for (int i = 0; i < 4; i++)
#pragma unroll
    for (int j = 0; j < 4; j++) acc[i][j] = (f32x4){0.f, 0.f, 0.f, 0.f};

  for (int k0 = 0; k0 < 1024; k0 += 64) {
#pragma unroll
    for (int r = 0; r < 8; r++) {
      int g = (r & 3) * 256 + tid;  // region-local granule 0..1023
      int row = g >> 3;
      int dg = (g & 7) ^ (row & 7);
      const bf16_t* src = (r < 4) ? (A + (size_t)(m0 + row) * 1024 + k0 + dg * 8)
                                  : (Bt + (size_t)(n0 + row) * 1024 + k0 + dg * 8);
      char* dst = ((r < 4) ? (char*)As : (char*)Bs) + ((r & 3) * 256 + wave * 64) * 16;
      gload_lds16(src, dst);
    }
    asm volatile("s_waitcnt vmcnt(0)" ::: "memory");
    __syncthreads();
#pragma unroll
    for (int ks = 0; ks < 2; ks++) {
      bf16x8 af[4], bfr[4];
#pragma unroll
      for (int i = 0; i < 4; i++) {
        af[i] = *(const bf16x8*)(As + ((wm + i * 16 + ln) * 8 + ((ks * 4 + lq) ^ swz)) * 8);
        bfr[i] = *(const bf16x8*)(Bs + ((wn + i * 16 + ln) * 8 + ((ks * 4 + lq) ^ swz)) * 8);
      }
#pragma unroll
      for (int i = 0; i < 4; i++)
#pragma unroll
        for (int j = 0; j < 4; j++)
          acc[i][j] = __builtin_amdgcn_mfma_f32_16x16x32_bf16(af[i], bfr[j], acc[i][j], 0, 0, 0);
    }
    __syncthreads();
  }

  if (isq) {
#pragma unroll
    for (int i = 0; i < 4; i++)
#pragma unroll
      for (int j = 0; j < 4; j++)
#pragma unroll
        for (int r = 0; r < 4; r++) {
          int row = m0 + wm + i * 16 + lq * 4 + r;
          int col = n0 + wn + j * 16 + ln;
          q12[(size_t)row * 2048 + col] = to_bf16(acc[i][j][r]);
        }
  } else {
    const int col0 = n0 + wn;
    const int part3 = col0 >> 10;  // 0:k1, 1:k2, 2:v
    const int h = (col0 >> 6) & 15;
    const int b = m0 >> 10;
    const int bh = b * 16 + h;
    if (part3 < 2) {
      const float* kn = part3 ? kn2 : kn1;
      bf16_t* dst = part3 ? k2h : k1h;
      float kw[4];
#pragma unroll
      for (int j = 0; j < 4; j++) kw[j] = kn[j * 16 + ln];
#pragma unroll
      for (int i = 0; i < 4; i++)
#pragma unroll
        for (int r = 0; r < 4; r++) {
          float ss = 0.f;
#pragma unroll
          for (int j = 0; j < 4; j++) ss += acc[i][j][r] * acc[i][j][r];
          ss += __shfl_xor(ss, 1, 64);
          ss += __shfl_xor(ss, 2, 64);
          ss += __shfl_xor(ss, 4, 64);
          ss += __shfl_xor(ss, 8, 64);
          float rstd = rsqrtf(ss * (1.f / 64.f) + 1e-5f);
          int m = m0 + wm + i * 16 + lq * 4 + r;
          int t = m & 1023;
          size_t base = ((size_t)bh * 1024 + t) * 64;
#pragma unroll
          for (int j = 0; j < 4; j++)
            dst[base + j * 16 + ln] = to_bf16(acc[i][j][r] * rstd * kw[j]);
        }
    } else {
      // V: vt'[bh][d][t'], t' permuted within each 32-block:
      // kv = h16*16 + lqw*4 + r  ->  t' = lqw*8 + h16*4 + r
      bf16_t* obase = vt + (size_t)bh * 65536;
#pragma unroll
      for (int i = 0; i < 4; i++) {
        int t0 = (m0 & 1023) + wm + i * 16 + lq * 4;
        int tp = (t0 & ~31) | (((t0 >> 2) & 3) << 3) | (((t0 >> 4) & 1) << 2);
#pragma unroll
        for (int j = 0; j < 4; j++) {
          bf16x4 pv;
#pragma unroll
          for (int r = 0; r < 4; r++) pv[r] = to_bf16(acc[i][j][r]);
          *(bf16x4*)(obase + (size_t)(j * 16 + ln) * 1024 + tp) = pv;
        }
      }
    }
  }
}

// ---------------- bf16 GEMM 128x64 tile (fp32 out), XCD-supertiled, BK=64, swizzled ----------------
__global__ __launch_bounds__(256, 2) void k_gemm64(const bf16_t* __restrict__ A,
                                                   const bf16_t* __restrict__ Bt,
                                                   float* __restrict__ C, int N, int K) {
  __shared__ bf16_t As[128 * 64];
  __shared__ bf16_t Bs[64 * 64];
  const int tid = threadIdx.x;
  const int wave = tid >> 6, lane = tid & 63;
  const int ln = lane & 15, lq = lane >> 4;
  const int swz = ln & 7;
  const int fid = blockIdx.x;             // flat 512
  const int xcd = fid & 7, l = fid >> 3;  // 0..63
  const int lx = l & 1, ly = (l >> 1) & 15, yh = l >> 5;
  const int n0 = (xcd * 2 + lx) * 64;
  const int m0 = (yh * 16 + ly) * 128;
  const int wm = wave * 32;
  f32x4 acc[2][4];
#pragma unroll
  for (int i = 0; i < 2; i++)
#pragma unroll
    for (int j = 0; j < 4; j++) acc[i][j] = (f32x4){0.f, 0.f, 0.f, 0.f};

  for (int k0 = 0; k0 < K; k0 += 64) {
#pragma unroll
    for (int r = 0; r < 6; r++) {
      int g = ((r < 4) ? (r & 3) : (r - 4)) * 256 + tid;
      int row = g >> 3;
      int dg = (g & 7) ^ (row & 7);
      const bf16_t* src = (r < 4) ? (A + (size_t)(m0 + row) * K + k0 + dg * 8)
                                  : (Bt + (size_t)(n0 + row) * K + k0 + dg * 8);
      char* dst = ((r < 4) ? (char*)As + (r & 3) * 4096 : (char*)Bs + (r - 4) * 4096) +
                  (wave * 64) * 16;
      gload_lds16(src, dst);
    }
    asm volatile("s_waitcnt vmcnt(0)" ::: "memory");
    __syncthreads();
#pragma unroll
    for (int ks = 0; ks < 2; ks++) {
      bf16x8 af[2], bfr[4];
#pragma unroll
      for (int i = 0; i < 2; i++)
        af[i] = *(const bf16x8*)(As + ((wm + i * 16 + ln) * 8 + ((ks * 4 + lq) ^ swz)) * 8);
#pragma unroll
      for (int j = 0; j < 4; j++)
        bfr[j] = *(const bf16x8*)(Bs + ((j * 16 + ln) * 8 + ((ks * 4 + lq) ^ swz)) * 8);
#pragma unroll
      for (int i = 0; i < 2; i++)
#pragma unroll
        for (int j = 0; j < 4; j++)
          acc[i][j] = __builtin_amdgcn_mfma_f32_16x16x32_bf16(af[i], bfr[j], acc[i][j], 0, 0, 0);
    }
    __syncthreads();
  }
#pragma unroll
  for (int i = 0; i < 2; i++)
#pragma unroll
    for (int j = 0; j < 4; j++)
#pragma unroll
      for (int r = 0; r < 4; r++) {
        int row = m0 + wm + i * 16 + lq * 4 + r;
        int col = n0 + j * 16 + ln;
        C[(size_t)row * N + col] = acc[i][j][r];
      }
}

// ---------------- fused dual-stream flash attention + GN partial stats ----------------
// grid (64=bh, 16=qblock); block 128 = 2 waves x 32 q-rows -> 1024 blocks, 4/CU.
// 64-KV chunks (24 KB LDS). __launch_bounds__(128,2) -> VGPR cap 256, no spill.
__global__ __launch_bounds__(128, 2) void k_attn2(const bf16_t* __restrict__ q12,
                                                  const bf16_t* __restrict__ k1h,
                                                  const bf16_t* __restrict__ k2h,
                                                  const bf16_t* __restrict__ vt,
                                                  const float* __restrict__ qn1,
                                                  const float* __restrict__ qn2,
                                                  const float* __restrict__ lmb,
                                                  bf16_t* __restrict__ y,
                                                  float* __restrict__ part) {
  __shared__ bf16_t Ks[2][4096];  // [kv][d] XOR-swizzled 16B granules
  __shared__ bf16_t Vs[4096];     // [d][t'] XOR-swizzled 16B granules
  __shared__ float red[4];
  const int tid = threadIdx.x;
  const int wave = tid >> 6, lane = tid & 63;
  const int ln = lane & 15, lq = lane >> 4;
  const int swz = ln & 7;
  const int bh = blockIdx.x;
  const int b = bh >> 4, h = bh & 15;
  const int q0 = blockIdx.y * 64 + wave * 32;
  const bf16_t* kb[2] = {k1h + (size_t)bh * 65536, k2h + (size_t)bh * 65536};
  const bf16_t* vb = vt + (size_t)bh * 65536;

  // ---- Q load (2 streams x 2 m-tiles) + fused RMSNorm * qn * (0.125*log2e) ----
  bf16x8 qf[2][2][2];  // [stream][mt][ks]
#pragma unroll
  for (int st = 0; st < 2; st++)
#pragma unroll
    for (int mt = 0; mt < 2; mt++)
#pragma unroll
      for (int ks = 0; ks < 2; ks++)
        qf[st][mt][ks] = *(const bf16x8*)(q12 + (size_t)(b * 1024 + q0 + mt * 16 + ln) * 2048 +
                                          st * 1024 + h * 64 + ks * 32 + lq * 8);
#pragma unroll
  for (int st = 0; st < 2; st++)
#pragma unroll
    for (int mt = 0; mt < 2; mt++) {
      const float* qn = st ? qn2 : qn1;
      float ssq = 0.f;
#pragma unroll
      for (int ks = 0; ks < 2; ks++)
#pragma unroll
        for (int j = 0; j < 8; j++) {
          float v = bf2f(qf[st][mt][ks][j]);
          ssq += v * v;
        }
      ssq += __shfl_xor(ssq, 16, 64);
      ssq += __shfl_xor(ssq, 32, 64);
      float rr = rsqrtf(ssq * (1.f / 64.f) + 1e-5f) * (0.125f * 1.44269504f);
#pragma unroll
      for (int ks = 0; ks < 2; ks++)
#pragma unroll
        for (int j = 0; j < 8; j++)
          qf[st][mt][ks][j] = to_bf16(bf2f(qf[st][mt][ks][j]) * rr * qn[ks * 32 + lq * 8 + j]);
    }

  f32x4 O[2][2][4];  // [stream][mt][nt]
  float lp[2][2] = {{0.f, 0.f}, {0.f, 0.f}};
#pragma unroll
  for (int st = 0; st < 2; st++)
#pragma unroll
    for (int mt = 0; mt < 2; mt++)
#pragma unroll
      for (int nt = 0; nt < 4; nt++) O[st][mt][nt] = (f32x4){0.f, 0.f, 0.f, 0.f};

  for (int kv0 = 0; kv0 < TKV_; kv0 += 64) {
    __syncthreads();
    // stage K1, K2, V (8 KB each): 12 rounds x 128 threads x 16 B
#pragma unroll
    for (int r = 0; r < 12; r++) {
      int reg = r >> 2;             // 0:K1, 1:K2, 2:V
      int g = (r & 3) * 128 + tid;  // region-local granule 0..511
      int row = g >> 3;
      int dg = (g & 7) ^ (row & 7);
      const bf16_t* src = (reg < 2) ? (kb[reg] + (size_t)(kv0 + row) * 64 + dg * 8)
                                    : (vb + (size_t)row * 1024 + kv0 + dg * 8);
      char* dst = ((reg < 2) ? (char*)Ks[reg] : (char*)Vs) + ((r & 3) * 128 + wave * 64) * 16;
      gload_lds16(src, dst);
    }
    asm volatile("s_waitcnt vmcnt(0)" ::: "memory");
    __syncthreads();

    // V B-frags: ONE b128 per (u,nt), shared by both streams and both m-tiles
    bf16x8 vf[2][4];
#pragma unroll
    for (int u = 0; u < 2; u++)
#pragma unroll
      for (int nt = 0; nt < 4; nt++)
        vf[u][nt] = *(const bf16x8*)(Vs + ((nt * 16 + ln) * 8 + ((u * 4 + lq) ^ swz)) * 8);

#pragma unroll
    for (int st = 0; st < 2; st++) {
      bf16x8 kf[2][4];
#pragma unroll
      for (int ks = 0; ks < 2; ks++)
#pragma unroll
        for (int t = 0; t < 4; t++)
          kf[ks][t] = *(const bf16x8*)(&Ks[st][((t * 16 + ln) * 8 + ((ks * 4 + lq) ^ swz)) * 8]);
#pragma unroll
      for (int mt = 0; mt < 2; mt++) {
        f32x4 s[4];
#pragma unroll
        for (int t = 0; t < 4; t++) s[t] = (f32x4){0.f, 0.f, 0.f, 0.f};
#pragma unroll
        for (int ks = 0; ks < 2; ks++)
#pragma unroll
          for (int t = 0; t < 4; t++)
            s[t] = __builtin_amdgcn_mfma_f32_16x16x32_bf16(kf[ks][t], qf[st][mt][ks], s[t], 0, 0, 0);
        uint32_t pfu[2][4];
        float l = 0.f;
#pragma unroll
        for (int t = 0; t < 4; t++) {
          float e0 = EXP2F(s[t][0]), e1 = EXP2F(s[t][1]);
          float e2 = EXP2F(s[t][2]), e3 = EXP2F(s[t][3]);
          l += (e0 + e1) + (e2 + e3);
          pfu[t >> 1][(t & 1) * 2] = pack_bf16_trunc(e0, e1);
          pfu[t >> 1][(t & 1) * 2 + 1] = pack_bf16_trunc(e2, e3);
        }
        lp[st][mt] += l;
#pragma unroll
        for (int u = 0; u < 2; u++) {
          bf16x8 pf = __builtin_bit_cast(bf16x8, *(uint4*)pfu[u]);
#pragma unroll
          for (int nt = 0; nt < 4; nt++)
            O[st][mt][nt] =
                __builtin_amdgcn_mfma_f32_16x16x32_bf16(pf, vf[u][nt], O[st][mt][nt], 0, 0, 0);
        }
      }
    }
  }

  float c = log1pf(__expf(lmb[h]));
  float s_acc = 0.f, ss_acc = 0.f;
#pragma unroll
  for (int mt = 0; mt < 2; mt++) {
    float linv[2][4];
#pragma unroll
    for (int st = 0; st < 2; st++) {
      float l = lp[st][mt];
      l += __shfl_xor(l, 16, 64);
      l += __shfl_xor(l, 32, 64);
#pragma unroll
      for (int r = 0; r < 4; r++) linv[st][r] = 1.f / __shfl(l, lq * 4 + r, 64);
    }
#pragma unroll
    for (int nt = 0; nt < 4; nt++)
#pragma unroll
      for (int r = 0; r < 4; r++) {
        size_t a = ((size_t)bh * TQ_ + q0 + mt * 16 + lq * 4 + r) * 64 + nt * 16 + ln;
        float val = O[0][mt][nt][r] * linv[0][r] - c * O[1][mt][nt][r] * linv[1][r];
        s_acc += val;
        ss_acc += val * val;
        y[a] = to_bf16(val);
      }
  }
  // GN partial stats: wave-reduce -> LDS -> one atomic pair per block
#pragma unroll
  for (int m = 1; m < 64; m <<= 1) {
    s_acc += __shfl_xor(s_acc, m, 64);
    ss_acc += __shfl_xor(ss_acc, m, 64);
  }
  if (lane == 0) {
    red[wave] = s_acc;
    red[2 + wave] = ss_acc;
  }
  __syncthreads();
  if (tid == 0) {
    atomicAdd(&part[bh * 2], red[0] + red[1]);
    atomicAdd(&part[bh * 2 + 1], red[2] + red[3]);
  }
}

// ---------------- GroupNorm apply (stats from part) + layout to (B,TQ,D) bf16 ----------------
__global__ __launch_bounds__(256) void k_gn_apply(const bf16_t* __restrict__ y,
                                                  const float* __restrict__ part,
                                                  const float* __restrict__ gw,
                                                  const float* __restrict__ gb,
                                                  bf16_t* __restrict__ yn) {
  int idx = blockIdx.x * 256 + threadIdx.x;
  int i = idx * 8;
  int bh = i >> 16;
  int h = bh & 15, b = bh >> 4;
  float S = part[bh * 2], SS = part[bh * 2 + 1];
  float mean = S * (1.f / 65536.f);
  float var = SS * (1.f / 65536.f) - mean * mean;
  float rstd = rsqrtf(var + 1e-5f);
  bf16x8 a = *(const bf16x8*)(y + i);
  int rem = i & 65535;
  int t = rem >> 6, d = rem & 63;
  bf16x8 o;
#pragma unroll
  for (int j = 0; j < 8; j++) {
    float f = (bf2f(a[j]) - mean) * rstd * gw[h * 64 + d + j] + gb[h * 64 + d + j];
    o[j] = to_bf16(f);
  }
  *(bf16x8*)(yn + ((size_t)(b * 1024 + t)) * 1024 + h * 64 + d) = o;
}

extern "C" void kernel_launch(void* const* d_in, const int* in_sizes, int n_in,
                              void* d_out, int out_size, void* d_ws, size_t ws_size,
                              hipStream_t stream) {
  const float* x_q = (const float*)d_in[0];
  const float* x_kv = (const float*)d_in[1];
  const float* Wq = (const float*)d_in[2];
  const float* Wkv = (const float*)d_in[3];
  const float* Wc = (const float*)d_in[4];
  const float* qn1 = (const float*)d_in[5];
  const float* kn1 = (const float*)d_in[6];
  const float* qn2 = (const float*)d_in[7];
  const float* kn2 = (const float*)d_in[8];
  const float* gn_w = (const float*)d_in[9];
  const float* gn_b = (const float*)d_in[10];
  const float* lmb = (const float*)d_in[11];

  const size_t MB = (size_t)1 << 20;
  char* ws = (char*)d_ws;
  bf16_t* xq_bf = (bf16_t*)(ws + 0 * MB);
  bf16_t* xkv_bf = (bf16_t*)(ws + 8 * MB);
  bf16_t* Wqt = (bf16_t*)(ws + 16 * MB);
  bf16_t* Wkvt = (bf16_t*)(ws + 20 * MB);
  bf16_t* Wct = (bf16_t*)(ws + 26 * MB);
  bf16_t* q12 = (bf16_t*)(ws + 28 * MB);
  bf16_t* k1h = (bf16_t*)(ws + 44 * MB);
  bf16_t* k2h = (bf16_t*)(ws + 52 * MB);
  bf16_t* vt = (bf16_t*)(ws + 60 * MB);
  bf16_t* y = (bf16_t*)(ws + 68 * MB);
  bf16_t* yn = (bf16_t*)(ws + 76 * MB);
  float* part = (float*)(ws + 84 * MB);  // 128 floats

  k_prep<<<14336, 256, 0, stream>>>(x_q, x_kv, Wq, Wkv, Wc, xq_bf, xkv_bf, Wqt, Wkvt, Wct,
                                    part);
  k_gemm_qkv<<<1280, 256, 0, stream>>>(xq_bf, xkv_bf, Wqt, Wkvt, kn1, kn2, q12, k1h, k2h,
                                       vt);
  k_attn2<<<dim3(64, 16), 128, 0, stream>>>(q12, k1h, k2h, vt, qn1, qn2, lmb, y, part);
  k_gn_apply<<<2048, 256, 0, stream>>>(y, part, gn_w, gn_b, yn);
  k_gemm64<<<512, 256, 0, stream>>>(yn, Wct, (float*)d_out, 1024, 1024);
}